// Round 1
// baseline (250.136 us; speedup 1.0000x reference)
//
#include <hip/hip_runtime.h>

// SNN membrane scan + spike + double-cumsum, fused single pass.
// T=1024 sequential per channel; B*N=16384 independent channels -> 1 thread each.
// 256 blocks x 64 threads = 1 wave per CU: latency hiding via 4-stage register
// pipeline (quad-buffered prefetch of 16 timesteps per stage).

#define T_LEN 1024
#define N_IN  512
#define BN    16384   // BATCH * N_IN
#define U     16      // timesteps per pipeline stage

struct Buf { float c[U]; float v[U]; };

__device__ __forceinline__ void prefetch(Buf& b, const float* __restrict__ cp,
                                         const float* __restrict__ vp, int t0) {
    const float* __restrict__ c = cp + t0 * BN;
    const float* __restrict__ v = vp + t0 * BN;
#pragma unroll
    for (int u = 0; u < U; ++u) {
        b.c[u] = c[u * BN];
        b.v[u] = v[u * BN];
    }
}

__device__ __forceinline__ void process(const Buf& b, float beta, float& m, int& c1,
                                        int& z, float* __restrict__ gp,
                                        float* __restrict__ zp, int t0) {
#pragma unroll
    for (int u = 0; u < U; ++u) {
        m = fmaf(beta, m, b.c[u]);          // matches reference beta*m + c (fp-contract)
        c1 += (m >= b.v[u]) ? 1 : 0;        // spike = Heaviside(m - vth); exact equiv
        z  += c1;                           // double cumsum; exact in int (max ~5.2e5)
        gp[(t0 + u) * BN] = (z == 1) ? 1.0f : 0.0f;
        zp[(t0 + u) * BN] = (float)z;
    }
}

__global__ __launch_bounds__(64, 1) void snn_scan(
        const float* __restrict__ cur, const float* __restrict__ beta,
        const float* __restrict__ vini, const float* __restrict__ vth,
        float* __restrict__ gz, float* __restrict__ zo, float* __restrict__ ml)
{
    const int i = blockIdx.x * 64 + threadIdx.x;   // channel id 0..BN-1 (= b*N + n)
    const float bta = beta[i & (N_IN - 1)];
    float m = vini[i];
    int c1 = 0, z = 0;

    const float* cp = cur + i;
    const float* vp = vth + i;
    float* gp = gz + i;
    float* zp = zo + i;

    Buf b0, b1, b2, b3;
    prefetch(b0, cp, vp, 0);
    prefetch(b1, cp, vp, U);
    prefetch(b2, cp, vp, 2 * U);
    prefetch(b3, cp, vp, 3 * U);

    for (int t0 = 0; t0 < T_LEN; t0 += 4 * U) {
        process(b0, bta, m, c1, z, gp, zp, t0);
        if (t0 + 4 * U < T_LEN) prefetch(b0, cp, vp, t0 + 4 * U);
        process(b1, bta, m, c1, z, gp, zp, t0 + U);
        if (t0 + 5 * U < T_LEN) prefetch(b1, cp, vp, t0 + 5 * U);
        process(b2, bta, m, c1, z, gp, zp, t0 + 2 * U);
        if (t0 + 6 * U < T_LEN) prefetch(b2, cp, vp, t0 + 6 * U);
        process(b3, bta, m, c1, z, gp, zp, t0 + 3 * U);
        if (t0 + 7 * U < T_LEN) prefetch(b3, cp, vp, t0 + 7 * U);
    }
    ml[i] = m;   // m_last (B,N)
}

extern "C" void kernel_launch(void* const* d_in, const int* in_sizes, int n_in,
                              void* d_out, int out_size, void* d_ws, size_t ws_size,
                              hipStream_t stream) {
    const float* cur  = (const float*)d_in[0];   // (T,B,N) fp32
    const float* beta = (const float*)d_in[1];   // (N,)
    const float* vini = (const float*)d_in[2];   // (B,N)
    const float* vth  = (const float*)d_in[3];   // (T,B,N)
    float* gz = (float*)d_out;                       // (T,B,N)
    float* zo = gz + (size_t)T_LEN * BN;             // (T,B,N)
    float* ml = zo + (size_t)T_LEN * BN;             // (B,N)
    snn_scan<<<BN / 64, 64, 0, stream>>>(cur, beta, vini, vth, gz, zo, ml);
}